// Round 4
// baseline (17.065 us; speedup 1.0000x reference)
//
#include <hip/hip_runtime.h>
#include <hip/hip_bf16.h>

// PQC classifier: circuit output is independent of the batch input x.
// Analytic reduction:
//   <Z0> = cos(theta_rx), <Z1> = cos(theta_ry), <Z2> = <Z3> = 1
//   logits = (cos tx + cos ty, 2); out = log_softmax(logits) broadcast to (bsz, 2).
// Kernel = compute 2 uniform scalars, broadcast-store 8 MB.
//
// Experiment: same 8192 waves / one float4 store per thread as the 10.1 us
// round-0 config, but 512 workgroups x 1024 threads (4x fewer dispatch
// packets, still 32 waves/CU). Tests whether per-workgroup dispatch ramp is
// the ~9 us residual over the 1.2 us store time.

__global__ void __launch_bounds__(1024) pqc_broadcast_kernel(
        const float* __restrict__ theta_rx,
        const float* __restrict__ theta_ry,
        float* __restrict__ out,
        int n4) {
    float cx = __cosf(theta_rx[0]);
    float cy = __cosf(theta_ry[0]);
    // logits l0 = cx+cy, l1 = 2.  d = l0 - 2 in [-4, 0].
    float d  = cx + cy - 2.0f;
    float o1 = -__logf(1.0f + __expf(d));
    float o0 = d + o1;

    float4 v = make_float4(o0, o1, o0, o1);
    int i = blockIdx.x * blockDim.x + threadIdx.x;
    if (i < n4) {
        reinterpret_cast<float4*>(out)[i] = v;
    }
}

extern "C" void kernel_launch(void* const* d_in, const int* in_sizes, int n_in,
                              void* d_out, int out_size, void* d_ws, size_t ws_size,
                              hipStream_t stream) {
    // Inputs (setup_inputs order): x (bsz*16 f32), theta_rx (1), theta_ry (1), theta_rz (1).
    const float* theta_rx = (const float*)d_in[1];
    const float* theta_ry = (const float*)d_in[2];
    float* out = (float*)d_out;

    int n4 = out_size / 4;      // float4 chunks (out_size = 2^21 floats)
    int block = 1024;
    int grid = (n4 + block - 1) / block;  // 512 workgroups
    pqc_broadcast_kernel<<<grid, block, 0, stream>>>(theta_rx, theta_ry, out, n4);
}